// Round 6
// baseline (482.306 us; speedup 1.0000x reference)
//
#include <hip/hip_runtime.h>
#include <stdint.h>

#define TSTEPS 512
#define BATCH  4096
#define SROW 76                      /* LDS row stride in shorts (R18 bank fix) */
// R21 = R20 with compact2 FIXED. R20 failed (absmax 0.647) because the
// permlane asm had vdst/vsrc reversed and returned the wrong output
// (garbage halves). Correct semantics: permlane32_swap(vdst,vsrc):
//   new_vdst = [vdst.lanes0-31, vsrc.lanes0-31]
//   new_vsrc = [vdst.lanes32-63, vsrc.lanes32-63]
// compact2(a) = first result of swap(a[0],a[2]) / swap(a[1],a[3]):
//   lanes 0-31 -> (a0,a1) = rows rp,rp+1 (rp=0|4); lanes 32-63 -> lane-32's
//   (a2,a3) = rows rp,rp+1 (rp=2|6). rp = (lq&1)*4 + (lq>>1)*2.
// Structure (R20): grid 512 x 256thr, 8 rows/block, 2 async blocks/CU
// (anti-phase blocks fill each other's barrier/latency bubbles). MFMA
// A-tiles half-empty; EW/trans runs 4 elem/lane on ALL 64 lanes via
// permlane compaction (trans issue/SIMD unchanged ~40 insts). Each wave
// owns 2 j-tiles (ti=0,1).
// R19: 294 us steady, VALU 53.6 (trans floor ~640cyc/step), Mfma 22.6,
// idle ~45% phase-aligned stall. Perfect-overlap floor ~160 us.
// Failed variants: R9 swizzle-store, R11 x-in-LDS, R12 deep MFMA chains,
// R13 shared-rcp, R14 occupancy push (spill), R20 compact2 direction.

typedef __attribute__((ext_vector_type(8))) short bf16x8;
typedef __attribute__((ext_vector_type(4))) float f32x4;
typedef __attribute__((ext_vector_type(2))) float f32x2;
typedef __attribute__((ext_vector_type(2))) unsigned int u32x2;

#define SRZ (-1.4426950408889634f)   /* -log2(e): r,z gates */
#define SN  ( 2.8853900817779268f)   /* 2*log2(e): n gate   */

struct PX { f32x2 r[2], z[2], n[2]; };

__device__ __forceinline__ short f2bf(float f) {
    uint32_t u = __float_as_uint(f);
    uint32_t r = (u + 0x7fffu + ((u >> 16) & 1u)) >> 16;
    return (short)r;
}
__device__ __forceinline__ uint32_t cvt_pk_bf16(float a, float b) {
    uint32_t r;
    asm("v_cvt_pk_bf16_f32 %0, %1, %2" : "=v"(r) : "v"(a), "v"(b));
    return r;
}
__device__ __forceinline__ float fast_rcp(float x) { return __builtin_amdgcn_rcpf(x); }
#if __has_builtin(__builtin_amdgcn_exp2f)
__device__ __forceinline__ float exp2_fast(float x) { return __builtin_amdgcn_exp2f(x); }
#else
__device__ __forceinline__ float exp2_fast(float x) { return __expf(x * 0.6931471805599453f); }
#endif

__device__ __forceinline__ f32x2 fma2(f32x2 a, f32x2 b, f32x2 c) {
    return __builtin_elementwise_fma(a, b, c);
}
__device__ __forceinline__ f32x2 splat2(float s) { return (f32x2){s, s}; }
__device__ __forceinline__ f32x2 exp22(f32x2 y) {
    return (f32x2){exp2_fast(y[0]), exp2_fast(y[1])};
}
__device__ __forceinline__ f32x2 rcp2(f32x2 y) {
    return (f32x2){fast_rcp(y[0]), fast_rcp(y[1])};
}
__device__ __forceinline__ f32x2 sig2(f32x2 y) {
    return rcp2(exp22(y) + splat2(1.0f));
}
// fused z/n/h': h' = [A(B-1)+h(B+1)] / [(B+1)(A+1)], A=exp2(yz), B=exp2(yn)
__device__ __forceinline__ f32x2 gru_h(f32x2 yz, f32x2 yn, f32x2 h) {
    const f32x2 A = exp22(yz);
    const f32x2 B = exp22(yn);
    const f32x2 P = A * B;
    const f32x2 u = (P - A) + fma2(h, B, h);
    const f32x2 d = (P + A) + (B + splat2(1.0f));
    return u * rcp2(d);
}
__device__ __forceinline__ void bar_lgkm() {
    asm volatile("s_waitcnt lgkmcnt(0)\n\ts_barrier" ::: "memory");
}
// Compact half-empty MFMA acc: lanes 0-31 keep (a0,a1); lanes 32-63 get
// lane-32's (a2,a3). new_vdst of permlane32_swap = [vdst.lo, vsrc.lo].
__device__ __forceinline__ f32x2 compact2(f32x4 a) {
#if __has_builtin(__builtin_amdgcn_permlane32_swap)
    u32x2 r0 = __builtin_amdgcn_permlane32_swap(__float_as_uint(a[0]), __float_as_uint(a[2]), false, false);
    u32x2 r1 = __builtin_amdgcn_permlane32_swap(__float_as_uint(a[1]), __float_as_uint(a[3]), false, false);
    return (f32x2){__uint_as_float(r0[0]), __uint_as_float(r1[0])};
#else
    float u = a[0], s0 = a[2];
    asm volatile("v_permlane32_swap_b32 %0, %1" : "+v"(u), "+v"(s0));
    float v = a[1], s1 = a[3];
    asm volatile("v_permlane32_swap_b32 %0, %1" : "+v"(v), "+v"(s1));
    return (f32x2){u, v};
#endif
}

__global__ __launch_bounds__(256, 2) void gru_fused(
    const float* __restrict__ x,     // [T,B,2]
    const float* __restrict__ Wih0,  // [192,2]
    const float* __restrict__ Whh0,  // [192,64]
    const float* __restrict__ bih0,  // [192]
    const float* __restrict__ bhh0,  // [192]
    const float* __restrict__ Wih1,  // [192,64]
    const float* __restrict__ Whh1,  // [192,64]
    const float* __restrict__ bih1,  // [192]
    const float* __restrict__ bhh1,  // [192]
    const float* __restrict__ Wp,    // [128]
    const float* __restrict__ bp,    // [1]
    float* __restrict__ out)         // [B]
{
    const int tid  = threadIdx.x;
    const int wv   = tid >> 6;      // wave 0..3
    const int isL0 = (wv < 2);
    const int wj   = wv & 1;        // j-half this wave owns (32 cols)
    const int l    = tid & 63;
    const int lm   = l & 15;        // A-frag row / B col within tile
    const int lq   = l >> 4;        // frag K-quad
    const int rp   = (lq & 1) * 4 + (lq >> 1) * 2;  // EW row base: 0,4,2,6
    const int b0   = blockIdx.x * 8;
    const int jb   = wj * 32 + lm;  // j for ti=0; ti=1 adds 16

    __shared__ short h0A[2][16 * SROW];
    __shared__ short h1A[2][16 * SROW];
    __shared__ float Pf[8][64];

    for (int idx = tid; idx < 2 * 16 * SROW; idx += 256) {
        ((short*)h0A)[idx] = 0;
        ((short*)h1A)[idx] = 0;
    }
    __syncthreads();

    const int aoff = lm * SROW + lq * 8;  // shorts; +32 for K-half 1

    if (isL0) {
        // ================= layer-0 waves (0,1) =================
        bf16x8 w0[3][2][2];   // [gate][ti][K-half], gate-prescaled bf16
#pragma unroll
        for (int g = 0; g < 3; ++g) {
            const float sc = (g == 2) ? SN : SRZ;
#pragma unroll
            for (int ti = 0; ti < 2; ++ti) {
                const int row = g * 64 + jb + ti * 16;
#pragma unroll
                for (int q = 0; q < 2; ++q) {
                    const float* p = Whh0 + row * 64 + q * 32 + lq * 8;
                    bf16x8 vh;
#pragma unroll
                    for (int i = 0; i < 8; ++i) vh[i] = f2bf(p[i] * sc);
                    w0[g][ti][q] = vh;
                }
            }
        }
        float wr0s[2], wr1s[2], wz0s[2], wz1s[2], wn0s[2], wn1s[2], bns[2];
        float cb0[3][2];
#pragma unroll
        for (int ti = 0; ti < 2; ++ti) {
            const int jj = jb + ti * 16;
            wr0s[ti] = SRZ * Wih0[jj * 2 + 0];          wr1s[ti] = SRZ * Wih0[jj * 2 + 1];
            wz0s[ti] = SRZ * Wih0[(64 + jj) * 2 + 0];   wz1s[ti] = SRZ * Wih0[(64 + jj) * 2 + 1];
            wn0s[ti] = SN  * Wih0[(128 + jj) * 2 + 0];  wn1s[ti] = SN  * Wih0[(128 + jj) * 2 + 1];
            bns[ti]  = SN  * bih0[128 + jj];
            cb0[0][ti] = SRZ * (bih0[jj] + bhh0[jj]);
            cb0[1][ti] = SRZ * (bih0[64 + jj] + bhh0[64 + jj]);
            cb0[2][ti] = SN  * bhh0[128 + jj];
        }

        f32x2 hstv[2] = {{0.f, 0.f}, {0.f, 0.f}};

        // x pipeline: lane loads its 2 rows (rp, rp+1) x 2 features = f32x4.
        const float* xp = x + (size_t)(b0 + rp) * 2;
        f32x4 xE = *(const f32x4*)xp;                       // x(0)
        f32x4 xO = *(const f32x4*)(xp + (size_t)BATCH * 2); // x(1)
        xp += 2 * (size_t)BATCH * 2;                        // next load = x(2)

        PX pE, pO;
        {   // px(0)
            const f32x2 x0v = {xE[0], xE[2]}, x1v = {xE[1], xE[3]};
#pragma unroll
            for (int ti = 0; ti < 2; ++ti) {
                pE.r[ti] = fma2(splat2(wr0s[ti]), x0v, splat2(wr1s[ti]) * x1v);
                pE.z[ti] = fma2(splat2(wz0s[ti]), x0v, splat2(wz1s[ti]) * x1v);
                pE.n[ti] = fma2(splat2(wn0s[ti]), x0v, fma2(splat2(wn1s[ti]), x1v, splat2(bns[ti])));
            }
        }

        auto l0_step = [&](int pr, bool doload, PX& u, PX& d, f32x4& xl, const f32x4& xs) {
            const int pw = pr ^ 1;
            const bf16x8 a0 = *(const bf16x8*)&h0A[pr][aoff];
            const bf16x8 a1 = *(const bf16x8*)&h0A[pr][aoff + 32];
            if (doload) { xl = *(const f32x4*)xp; xp += (size_t)BATCH * 2; }
            f32x4 hg[3][2];
            __builtin_amdgcn_s_setprio(1);
#pragma unroll
            for (int ti = 0; ti < 2; ++ti)
#pragma unroll
                for (int g = 0; g < 3; ++g) {
                    const f32x4 ci = {cb0[g][ti], cb0[g][ti], cb0[g][ti], cb0[g][ti]};
                    f32x4 c;
                    c = __builtin_amdgcn_mfma_f32_16x16x32_bf16(a0, w0[g][ti][0], ci, 0, 0, 0);
                    hg[g][ti] = __builtin_amdgcn_mfma_f32_16x16x32_bf16(a1, w0[g][ti][1], c, 0, 0, 0);
                }
            __builtin_amdgcn_s_setprio(0);
            {   // px for next step (fills MFMA shadow)
                const f32x2 x0v = {xs[0], xs[2]}, x1v = {xs[1], xs[3]};
#pragma unroll
                for (int ti = 0; ti < 2; ++ti) {
                    d.r[ti] = fma2(splat2(wr0s[ti]), x0v, splat2(wr1s[ti]) * x1v);
                    d.z[ti] = fma2(splat2(wz0s[ti]), x0v, splat2(wz1s[ti]) * x1v);
                    d.n[ti] = fma2(splat2(wn0s[ti]), x0v, fma2(splat2(wn1s[ti]), x1v, splat2(bns[ti])));
                }
            }
#pragma unroll
            for (int ti = 0; ti < 2; ++ti) {
                const f32x2 hgr = compact2(hg[0][ti]);
                const f32x2 hgz = compact2(hg[1][ti]);
                const f32x2 hgn = compact2(hg[2][ti]);
                const f32x2 rv = sig2(hgr + u.r[ti]);
                const f32x2 hv = gru_h(hgz + u.z[ti], fma2(rv, hgn, u.n[ti]), hstv[ti]);
                hstv[ti] = hv;
                const uint32_t pk = cvt_pk_bf16(hv[0], hv[1]);
                const int jj = jb + ti * 16;
                h0A[pw][(rp + 0) * SROW + jj] = (short)(pk & 0xffffu);
                h0A[pw][(rp + 1) * SROW + jj] = (short)(pk >> 16);
            }
        };

        for (int tp = 0; tp < TSTEPS / 2; ++tp) {
            const bool dl = (tp < TSTEPS / 2 - 1);
            l0_step(0, dl, pE, pO, xE, xO);   // t = 2tp
            bar_lgkm();
            l0_step(1, dl, pO, pE, xO, xE);   // t = 2tp+1
            bar_lgkm();
        }
        // t=512: no L0 work

#pragma unroll
        for (int ti = 0; ti < 2; ++ti) {
            const int jj = jb + ti * 16;
            const float wp0 = Wp[jj];
            Pf[rp + 0][jj] = wp0 * hstv[ti][0];
            Pf[rp + 1][jj] = wp0 * hstv[ti][1];
        }
        __syncthreads();
        __syncthreads();
    } else {
        // ================= layer-1 waves (2,3) =================
        bf16x8 w1v[3][2][2], w2v[3][2][2];   // Wih1, Whh1
#pragma unroll
        for (int g = 0; g < 3; ++g) {
            const float sc = (g == 2) ? SN : SRZ;
#pragma unroll
            for (int ti = 0; ti < 2; ++ti) {
                const int row = g * 64 + jb + ti * 16;
#pragma unroll
                for (int q = 0; q < 2; ++q) {
                    const float* p1 = Wih1 + row * 64 + q * 32 + lq * 8;
                    const float* p2 = Whh1 + row * 64 + q * 32 + lq * 8;
                    bf16x8 v1, v2;
#pragma unroll
                    for (int i = 0; i < 8; ++i) {
                        v1[i] = f2bf(p1[i] * sc);
                        v2[i] = f2bf(p2[i] * sc);
                    }
                    w1v[g][ti][q] = v1; w2v[g][ti][q] = v2;
                }
            }
        }
        float cb1[3][2], ce2s[2];
#pragma unroll
        for (int ti = 0; ti < 2; ++ti) {
            const int jj = jb + ti * 16;
            cb1[0][ti] = SRZ * (bih1[jj] + bhh1[jj]);
            cb1[1][ti] = SRZ * (bih1[64 + jj] + bhh1[64 + jj]);
            cb1[2][ti] = SN  * bih1[128 + jj];
            ce2s[ti]   = SN  * bhh1[128 + jj];   // r-scaled part, in hg C-init
        }

        f32x2 hstv[2] = {{0.f, 0.f}, {0.f, 0.f}};

        auto l1_step = [&](int pr, bool doew, bool dowrite) {
            const int pw = pr ^ 1;
            const bf16x8 a00 = *(const bf16x8*)&h0A[pr][aoff];
            const bf16x8 a01 = *(const bf16x8*)&h0A[pr][aoff + 32];
            const bf16x8 a10 = *(const bf16x8*)&h1A[pr][aoff];
            const bf16x8 a11 = *(const bf16x8*)&h1A[pr][aoff + 32];
            f32x4 xg[3][2], hgv[3][2];
            __builtin_amdgcn_s_setprio(1);
#pragma unroll
            for (int ti = 0; ti < 2; ++ti)
#pragma unroll
                for (int g = 0; g < 3; ++g) {
                    const f32x4 ci = {cb1[g][ti], cb1[g][ti], cb1[g][ti], cb1[g][ti]};
                    f32x4 dd;
                    dd = __builtin_amdgcn_mfma_f32_16x16x32_bf16(a00, w1v[g][ti][0], ci, 0, 0, 0);
                    xg[g][ti] = __builtin_amdgcn_mfma_f32_16x16x32_bf16(a01, w1v[g][ti][1], dd, 0, 0, 0);
                    const float ev = (g == 2) ? ce2s[ti] : 0.0f;
                    const f32x4 ei = {ev, ev, ev, ev};
                    f32x4 e;
                    e = __builtin_amdgcn_mfma_f32_16x16x32_bf16(a10, w2v[g][ti][0], ei, 0, 0, 0);
                    hgv[g][ti] = __builtin_amdgcn_mfma_f32_16x16x32_bf16(a11, w2v[g][ti][1], e, 0, 0, 0);
                }
            __builtin_amdgcn_s_setprio(0);

            if (doew) {
#pragma unroll
                for (int ti = 0; ti < 2; ++ti) {
                    const f32x2 r2  = compact2(xg[0][ti] + hgv[0][ti]);
                    const f32x2 z2  = compact2(xg[1][ti] + hgv[1][ti]);
                    const f32x2 xn2 = compact2(xg[2][ti]);
                    const f32x2 hn2 = compact2(hgv[2][ti]);
                    const f32x2 rv = sig2(r2);
                    const f32x2 hv = gru_h(z2, fma2(rv, hn2, xn2), hstv[ti]);
                    hstv[ti] = hv;
                    if (dowrite) {
                        const uint32_t pk = cvt_pk_bf16(hv[0], hv[1]);
                        const int jj = jb + ti * 16;
                        h1A[pw][(rp + 0) * SROW + jj] = (short)(pk & 0xffffu);
                        h1A[pw][(rp + 1) * SROW + jj] = (short)(pk >> 16);
                    }
                }
            }
        };

        for (int tp = 0; tp < TSTEPS / 2; ++tp) {
            l1_step(0, tp > 0, true);   // t = 2tp
            bar_lgkm();
            l1_step(1, true, true);     // t = 2tp+1
            bar_lgkm();
        }
        l1_step(0, true, false);        // t = 512: final h1 update, no store

        __syncthreads();                // Pf written by L0 waves
#pragma unroll
        for (int ti = 0; ti < 2; ++ti) {
            const int jj = jb + ti * 16;
            const float wp1 = Wp[64 + jj];
            Pf[rp + 0][jj] += wp1 * hstv[ti][0];
            Pf[rp + 1][jj] += wp1 * hstv[ti][1];
        }
        __syncthreads();
    }

    // ---- final reduce: out[b] = sum_j Pf[row][j] + bp ----
    if (tid < 8) {
        float s = bp[0];
#pragma unroll 8
        for (int k = 0; k < 64; ++k) s += Pf[tid][k];
        out[b0 + tid] = s;
    }
}

extern "C" void kernel_launch(void* const* d_in, const int* in_sizes, int n_in,
                              void* d_out, int out_size, void* d_ws, size_t ws_size,
                              hipStream_t stream) {
    (void)in_sizes; (void)n_in; (void)out_size; (void)d_ws; (void)ws_size;
    gru_fused<<<dim3(BATCH / 8), dim3(256), 0, stream>>>(
        (const float*)d_in[0], (const float*)d_in[1], (const float*)d_in[2],
        (const float*)d_in[3], (const float*)d_in[4], (const float*)d_in[5],
        (const float*)d_in[6], (const float*)d_in[7], (const float*)d_in[8],
        (const float*)d_in[9], (const float*)d_in[10], (float*)d_out);
}

// Round 7
// 451.125 us; speedup vs baseline: 1.0691x; 1.0691x over previous
//
#include <hip/hip_runtime.h>
#include <stdint.h>

#define TSTEPS 512
#define BATCH  4096
#define SROW 76                      /* LDS row stride in shorts (R18 bank fix) */
// R22: 2 blocks/CU x 512thr x 8 rows, 4 waves/SIMD WITH role diversity.
// R21 failed perf (466us): 4-wave blocks put same-role waves on each SIMD
// (waves 0..3 -> SIMDs 0..3), identical code streams aligned perfectly ->
// no mutual latency hiding + 2x MFMA cost. Fix: 8-wave blocks (4 L0 + 4 L1)
// so every SIMD hosts L0+L1 from each of the 2 resident blocks (4 streams,
// mixed roles). Trans issue/SIMD conserved (40 insts/step). MFMA 2x vs R19
// (half-empty 8-row tiles) -- matrix pipe has headroom. launch_bounds(512,4)
// caps VGPR at 128 for 2 blocks/CU.
// EW: permlane-compacted (R21-verified): lanes0-31 keep (a0,a1), lanes32-63
// get lane-32's (a2,a3); rp = (lq&1)*4+(lq>>1)*2 -> rows {rp,rp+1} @ j.
// R19: 294us steady (VALU 53.6, Mfma 22.6, ~45% idle, 2 waves/SIMD).
// R21: 466us (structure wrong). Perfect-overlap trans floor ~160-190us.
// Failed: R9 swizzle-store, R11 x-in-LDS, R12 deep MFMA chains, R13
// shared-rcp, R14 occupancy push, R20 compact2 dir, R21 same-role SIMDs.

typedef __attribute__((ext_vector_type(8))) short bf16x8;
typedef __attribute__((ext_vector_type(4))) float f32x4;
typedef __attribute__((ext_vector_type(2))) float f32x2;
typedef __attribute__((ext_vector_type(2))) unsigned int u32x2;

#define SRZ (-1.4426950408889634f)   /* -log2(e): r,z gates */
#define SN  ( 2.8853900817779268f)   /* 2*log2(e): n gate   */

struct PX { f32x2 r, z, n; };

__device__ __forceinline__ short f2bf(float f) {
    uint32_t u = __float_as_uint(f);
    uint32_t r = (u + 0x7fffu + ((u >> 16) & 1u)) >> 16;
    return (short)r;
}
__device__ __forceinline__ uint32_t cvt_pk_bf16(float a, float b) {
    uint32_t r;
    asm("v_cvt_pk_bf16_f32 %0, %1, %2" : "=v"(r) : "v"(a), "v"(b));
    return r;
}
__device__ __forceinline__ float fast_rcp(float x) { return __builtin_amdgcn_rcpf(x); }
#if __has_builtin(__builtin_amdgcn_exp2f)
__device__ __forceinline__ float exp2_fast(float x) { return __builtin_amdgcn_exp2f(x); }
#else
__device__ __forceinline__ float exp2_fast(float x) { return __expf(x * 0.6931471805599453f); }
#endif

__device__ __forceinline__ f32x2 fma2(f32x2 a, f32x2 b, f32x2 c) {
    return __builtin_elementwise_fma(a, b, c);
}
__device__ __forceinline__ f32x2 splat2(float s) { return (f32x2){s, s}; }
__device__ __forceinline__ f32x2 exp22(f32x2 y) {
    return (f32x2){exp2_fast(y[0]), exp2_fast(y[1])};
}
__device__ __forceinline__ f32x2 rcp2(f32x2 y) {
    return (f32x2){fast_rcp(y[0]), fast_rcp(y[1])};
}
__device__ __forceinline__ f32x2 sig2(f32x2 y) {
    return rcp2(exp22(y) + splat2(1.0f));
}
// fused z/n/h': h' = [A(B-1)+h(B+1)] / [(B+1)(A+1)], A=exp2(yz), B=exp2(yn)
__device__ __forceinline__ f32x2 gru_h(f32x2 yz, f32x2 yn, f32x2 h) {
    const f32x2 A = exp22(yz);
    const f32x2 B = exp22(yn);
    const f32x2 P = A * B;
    const f32x2 u = (P - A) + fma2(h, B, h);
    const f32x2 d = (P + A) + (B + splat2(1.0f));
    return u * rcp2(d);
}
__device__ __forceinline__ void bar_lgkm() {
    asm volatile("s_waitcnt lgkmcnt(0)\n\ts_barrier" ::: "memory");
}
// Compact half-empty MFMA acc: lanes 0-31 keep (a0,a1); lanes 32-63 get
// lane-32's (a2,a3). new_vdst of permlane32_swap = [vdst.lo, vsrc.lo].
// (R21-verified on hardware.)
__device__ __forceinline__ f32x2 compact2(f32x4 a) {
#if __has_builtin(__builtin_amdgcn_permlane32_swap)
    u32x2 r0 = __builtin_amdgcn_permlane32_swap(__float_as_uint(a[0]), __float_as_uint(a[2]), false, false);
    u32x2 r1 = __builtin_amdgcn_permlane32_swap(__float_as_uint(a[1]), __float_as_uint(a[3]), false, false);
    return (f32x2){__uint_as_float(r0[0]), __uint_as_float(r1[0])};
#else
    float u = a[0], s0 = a[2];
    asm volatile("v_permlane32_swap_b32 %0, %1" : "+v"(u), "+v"(s0));
    float v = a[1], s1 = a[3];
    asm volatile("v_permlane32_swap_b32 %0, %1" : "+v"(v), "+v"(s1));
    return (f32x2){u, v};
#endif
}

__global__ __launch_bounds__(512, 4) void gru_fused(
    const float* __restrict__ x,     // [T,B,2]
    const float* __restrict__ Wih0,  // [192,2]
    const float* __restrict__ Whh0,  // [192,64]
    const float* __restrict__ bih0,  // [192]
    const float* __restrict__ bhh0,  // [192]
    const float* __restrict__ Wih1,  // [192,64]
    const float* __restrict__ Whh1,  // [192,64]
    const float* __restrict__ bih1,  // [192]
    const float* __restrict__ bhh1,  // [192]
    const float* __restrict__ Wp,    // [128]
    const float* __restrict__ bp,    // [1]
    float* __restrict__ out)         // [B]
{
    const int tid  = threadIdx.x;
    const int wv   = tid >> 6;      // wave 0..7
    const int isL0 = (wv < 4);      // waves 0-3: L0; 4-7: L1 (SIMD i gets L0+L1)
    const int w4   = wv & 3;
    const int l    = tid & 63;
    const int lm   = l & 15;        // A-frag row / B col within tile
    const int lq   = l >> 4;        // frag K-quad
    const int rp   = (lq & 1) * 4 + (lq >> 1) * 2;  // EW row base: 0,4,2,6
    const int b0   = blockIdx.x * 8;
    const int j    = w4 * 16 + lm;  // hidden index this lane owns

    __shared__ short h0A[2][16 * SROW];   // rows 8-15 stay zero forever
    __shared__ short h1A[2][16 * SROW];
    __shared__ float Pf[8][64];

    for (int idx = tid; idx < 2 * 16 * SROW; idx += 512) {
        ((short*)h0A)[idx] = 0;
        ((short*)h1A)[idx] = 0;
    }
    __syncthreads();

    const int aoff = lm * SROW + lq * 8;  // shorts; +32 for K-half 1

    if (isL0) {
        // ================= layer-0 waves (0-3) =================
        bf16x8 w0[3][2];   // Whh0, gate-prescaled, single bf16
#pragma unroll
        for (int g = 0; g < 3; ++g) {
            const int row = g * 64 + j;
            const float sc = (g == 2) ? SN : SRZ;
#pragma unroll
            for (int q = 0; q < 2; ++q) {
                const float* p = Whh0 + row * 64 + q * 32 + lq * 8;
                bf16x8 vh;
#pragma unroll
                for (int i = 0; i < 8; ++i) vh[i] = f2bf(p[i] * sc);
                w0[g][q] = vh;
            }
        }
        const f32x2 wr0 = splat2(SRZ * Wih0[j * 2 + 0]), wr1 = splat2(SRZ * Wih0[j * 2 + 1]);
        const f32x2 wz0 = splat2(SRZ * Wih0[(64 + j) * 2 + 0]), wz1 = splat2(SRZ * Wih0[(64 + j) * 2 + 1]);
        const f32x2 wn0 = splat2(SN * Wih0[(128 + j) * 2 + 0]), wn1 = splat2(SN * Wih0[(128 + j) * 2 + 1]);
        const float cb[3] = { SRZ * (bih0[j] + bhh0[j]),
                              SRZ * (bih0[64 + j] + bhh0[64 + j]),
                              SN  * bhh0[128 + j] };
        const f32x2 bn = splat2(SN * bih0[128 + j]);

        f32x2 hst = {0.f, 0.f};

        // x pipeline: lane loads its 2 rows (rp, rp+1) x 2 feats = f32x4.
        const float* xp = x + (size_t)(b0 + rp) * 2;
        f32x4 xE = *(const f32x4*)xp;                       // x(0)
        f32x4 xO = *(const f32x4*)(xp + (size_t)BATCH * 2); // x(1)
        xp += 2 * (size_t)BATCH * 2;                        // next load = x(2)

        PX pE, pO;
        {   // px(0)
            const f32x2 x0v = {xE[0], xE[2]}, x1v = {xE[1], xE[3]};
            pE.r = fma2(wr0, x0v, wr1 * x1v);
            pE.z = fma2(wz0, x0v, wz1 * x1v);
            pE.n = fma2(wn0, x0v, fma2(wn1, x1v, bn));
        }

        auto l0_step = [&](int pr, bool doload, PX& u, PX& d, f32x4& xl, const f32x4& xs) {
            const int pw = pr ^ 1;
            const bf16x8 a0 = *(const bf16x8*)&h0A[pr][aoff];
            const bf16x8 a1 = *(const bf16x8*)&h0A[pr][aoff + 32];
            if (doload) { xl = *(const f32x4*)xp; xp += (size_t)BATCH * 2; }
            f32x4 hg[3];
            __builtin_amdgcn_s_setprio(1);
#pragma unroll
            for (int g = 0; g < 3; ++g) {
                const f32x4 ci = {cb[g], cb[g], cb[g], cb[g]};
                f32x4 c;
                c = __builtin_amdgcn_mfma_f32_16x16x32_bf16(a0, w0[g][0], ci, 0, 0, 0);
                hg[g] = __builtin_amdgcn_mfma_f32_16x16x32_bf16(a1, w0[g][1], c, 0, 0, 0);
            }
            __builtin_amdgcn_s_setprio(0);
            {   // px for next step (fills MFMA shadow)
                const f32x2 x0v = {xs[0], xs[2]}, x1v = {xs[1], xs[3]};
                d.r = fma2(wr0, x0v, wr1 * x1v);
                d.z = fma2(wz0, x0v, wz1 * x1v);
                d.n = fma2(wn0, x0v, fma2(wn1, x1v, bn));
            }
            const f32x2 hgr = compact2(hg[0]);
            const f32x2 hgz = compact2(hg[1]);
            const f32x2 hgn = compact2(hg[2]);
            const f32x2 rv = sig2(hgr + u.r);
            const f32x2 hv = gru_h(hgz + u.z, fma2(rv, hgn, u.n), hst);
            hst = hv;
            const uint32_t pk = cvt_pk_bf16(hv[0], hv[1]);
            h0A[pw][(rp + 0) * SROW + j] = (short)(pk & 0xffffu);
            h0A[pw][(rp + 1) * SROW + j] = (short)(pk >> 16);
        };

        for (int tp = 0; tp < TSTEPS / 2; ++tp) {
            const bool dl = (tp < TSTEPS / 2 - 1);
            l0_step(0, dl, pE, pO, xE, xO);   // t = 2tp
            bar_lgkm();
            l0_step(1, dl, pO, pE, xO, xE);   // t = 2tp+1
            bar_lgkm();
        }
        // t=512: no L0 work

        const float wp0 = Wp[j];
        Pf[rp + 0][j] = wp0 * hst[0];
        Pf[rp + 1][j] = wp0 * hst[1];
        __syncthreads();
        __syncthreads();
    } else {
        // ================= layer-1 waves (4-7) =================
        bf16x8 w1[3][2], w2[3][2];   // Wih1, Whh1, gate-prescaled bf16
#pragma unroll
        for (int g = 0; g < 3; ++g) {
            const int row = g * 64 + j;
            const float sc = (g == 2) ? SN : SRZ;
#pragma unroll
            for (int q = 0; q < 2; ++q) {
                const float* p1 = Wih1 + row * 64 + q * 32 + lq * 8;
                const float* p2 = Whh1 + row * 64 + q * 32 + lq * 8;
                bf16x8 v1, v2;
#pragma unroll
                for (int i = 0; i < 8; ++i) {
                    v1[i] = f2bf(p1[i] * sc);
                    v2[i] = f2bf(p2[i] * sc);
                }
                w1[g][q] = v1; w2[g][q] = v2;
            }
        }
        const float cb[3] = { SRZ * (bih1[j] + bhh1[j]),
                              SRZ * (bih1[64 + j] + bhh1[64 + j]),
                              SN  * bih1[128 + j] };
        // bhh1_n folded into hg1's C-init (multiplied by r later)
        const float ce2 = SN * bhh1[128 + j];

        f32x2 hst = {0.f, 0.f};

        auto l1_step = [&](int pr, bool doew, bool dowrite) {
            const int pw = pr ^ 1;
            const bf16x8 a00 = *(const bf16x8*)&h0A[pr][aoff];
            const bf16x8 a01 = *(const bf16x8*)&h0A[pr][aoff + 32];
            const bf16x8 a10 = *(const bf16x8*)&h1A[pr][aoff];
            const bf16x8 a11 = *(const bf16x8*)&h1A[pr][aoff + 32];
            f32x4 xg[3], hgv[3];
            __builtin_amdgcn_s_setprio(1);
#pragma unroll
            for (int g = 0; g < 3; ++g) {
                const float ev = (g == 2) ? ce2 : 0.0f;
                const f32x4 ei = {ev, ev, ev, ev};
                f32x4 e;
                e = __builtin_amdgcn_mfma_f32_16x16x32_bf16(a10, w2[g][0], ei, 0, 0, 0);
                hgv[g] = __builtin_amdgcn_mfma_f32_16x16x32_bf16(a11, w2[g][1], e, 0, 0, 0);
            }
#pragma unroll
            for (int g = 0; g < 3; ++g) {
                const f32x4 ci = {cb[g], cb[g], cb[g], cb[g]};
                f32x4 dd;
                dd = __builtin_amdgcn_mfma_f32_16x16x32_bf16(a00, w1[g][0], ci, 0, 0, 0);
                xg[g] = __builtin_amdgcn_mfma_f32_16x16x32_bf16(a01, w1[g][1], dd, 0, 0, 0);
            }
            __builtin_amdgcn_s_setprio(0);

            if (doew) {
                const f32x2 r2  = compact2(xg[0] + hgv[0]);
                const f32x2 z2  = compact2(xg[1] + hgv[1]);
                const f32x2 xn2 = compact2(xg[2]);
                const f32x2 hn2 = compact2(hgv[2]);
                const f32x2 rv = sig2(r2);
                const f32x2 hv = gru_h(z2, fma2(rv, hn2, xn2), hst);
                hst = hv;
                if (dowrite) {
                    const uint32_t pk = cvt_pk_bf16(hv[0], hv[1]);
                    h1A[pw][(rp + 0) * SROW + j] = (short)(pk & 0xffffu);
                    h1A[pw][(rp + 1) * SROW + j] = (short)(pk >> 16);
                }
            }
        };

        for (int tp = 0; tp < TSTEPS / 2; ++tp) {
            l1_step(0, tp > 0, true);   // t = 2tp
            bar_lgkm();
            l1_step(1, true, true);     // t = 2tp+1
            bar_lgkm();
        }
        l1_step(0, true, false);        // t = 512: final h1 update, no store

        __syncthreads();                // Pf written by L0 waves
        const float wp1 = Wp[64 + j];
        Pf[rp + 0][j] += wp1 * hst[0];
        Pf[rp + 1][j] += wp1 * hst[1];
        __syncthreads();
    }

    // ---- final reduce: out[b] = sum_j Pf[row][j] + bp ----
    if (tid < 8) {
        float s = bp[0];
#pragma unroll 8
        for (int k = 0; k < 64; ++k) s += Pf[tid][k];
        out[b0 + tid] = s;
    }
}

extern "C" void kernel_launch(void* const* d_in, const int* in_sizes, int n_in,
                              void* d_out, int out_size, void* d_ws, size_t ws_size,
                              hipStream_t stream) {
    (void)in_sizes; (void)n_in; (void)out_size; (void)d_ws; (void)ws_size;
    gru_fused<<<dim3(BATCH / 8), dim3(512), 0, stream>>>(
        (const float*)d_in[0], (const float*)d_in[1], (const float*)d_in[2],
        (const float*)d_in[3], (const float*)d_in[4], (const float*)d_in[5],
        (const float*)d_in[6], (const float*)d_in[7], (const float*)d_in[8],
        (const float*)d_in[9], (const float*)d_in[10], (float*)d_out);
}

// Round 8
// 339.928 us; speedup vs baseline: 1.4188x; 1.3271x over previous
//
#include <hip/hip_runtime.h>
#include <stdint.h>

#define TSTEPS 512
#define BATCH  4096
#define SROW 76                      /* LDS row stride in shorts (R18 bank fix) */
// R23 = R19 revert (measured best: 294us steady) + 2 order-only tweaks:
// (a) px computed BEFORE the MFMA cluster (fills ds_read lgkm window),
// (b) L1 reads split: h1 frags + hg MFMAs, then h0 frags + xg MFMAs
//     (halves post-barrier LDS burst: 24 -> 16 simultaneous b128/CU).
// WHY revert: R20-R22 (8-row, more waves/SIMD) all lose — with 16 rows/CU
// fixed, extra waves duplicate per-wave fixed overhead (+64% VALU cyc, R22)
// and double MFMA on half-empty tiles; TLP gain < overhead. R19 shape
// (16-row full tiles, 1 block/CU, 2 waves/SIMD, L0+L1 per SIMD) is the
// efficient point. Budget @R19 (1376 cyc/step): VALU busy 738 (trans ~320
// @1/4-rate, regular ~400), MFMA ~290 (overlapped), idle ~640 = LDS burst
// (~290) + read latency + serial EW chain, partially covered by 2 waves.
// Failed: R9 swizzle-store, R11 x-in-LDS, R12 deep MFMA chains, R13
// shared-rcp, R14 occupancy push, R20 compact2 dir, R21 same-role SIMDs,
// R22 8-row+4waves/SIMD (overhead duplication).

typedef __attribute__((ext_vector_type(8))) short bf16x8;
typedef __attribute__((ext_vector_type(4))) float f32x4;
typedef __attribute__((ext_vector_type(2))) float f32x2;

#define SRZ (-1.4426950408889634f)   /* -log2(e): r,z gates */
#define SN  ( 2.8853900817779268f)   /* 2*log2(e): n gate   */

struct PX { f32x2 gr0, gz0, gn0, gr1, gz1, gn1; };

__device__ __forceinline__ short f2bf(float f) {
    uint32_t u = __float_as_uint(f);
    uint32_t r = (u + 0x7fffu + ((u >> 16) & 1u)) >> 16;
    return (short)r;
}
// packed f32x2 -> 2x bf16 (RNE), lo = a, hi = b
__device__ __forceinline__ uint32_t cvt_pk_bf16(float a, float b) {
    uint32_t r;
    asm("v_cvt_pk_bf16_f32 %0, %1, %2" : "=v"(r) : "v"(a), "v"(b));
    return r;
}
__device__ __forceinline__ float fast_rcp(float x) { return __builtin_amdgcn_rcpf(x); }
#if __has_builtin(__builtin_amdgcn_exp2f)
__device__ __forceinline__ float exp2_fast(float x) { return __builtin_amdgcn_exp2f(x); }
#else
__device__ __forceinline__ float exp2_fast(float x) { return __expf(x * 0.6931471805599453f); }
#endif

__device__ __forceinline__ f32x2 fma2(f32x2 a, f32x2 b, f32x2 c) {
    return __builtin_elementwise_fma(a, b, c);
}
__device__ __forceinline__ f32x2 splat2(float s) { return (f32x2){s, s}; }
__device__ __forceinline__ f32x2 exp22(f32x2 y) {
    return (f32x2){exp2_fast(y[0]), exp2_fast(y[1])};
}
__device__ __forceinline__ f32x2 rcp2(f32x2 y) {
    return (f32x2){fast_rcp(y[0]), fast_rcp(y[1])};
}
// sigmoid of pre-scaled arg: rcp(1 + exp2(y))
__device__ __forceinline__ f32x2 sig2(f32x2 y) {
    return rcp2(exp22(y) + splat2(1.0f));
}
// fused z/n/h' update: yz pre-scaled by SRZ, yn pre-scaled by SN.
// z = 1/(1+A), n = (B-1)/(B+1); h' = (1-z)n + z*h
//    = [A(B-1) + h(B+1)] / [(B+1)(A+1)]
__device__ __forceinline__ f32x2 gru_h(f32x2 yz, f32x2 yn, f32x2 h) {
    const f32x2 A = exp22(yz);
    const f32x2 B = exp22(yn);
    const f32x2 P = A * B;
    const f32x2 u = (P - A) + fma2(h, B, h);            // A*B - A + h*B + h
    const f32x2 d = (P + A) + (B + splat2(1.0f));       // A*B + A + B + 1
    return u * rcp2(d);
}
// in-loop barrier: drain LDS only (keep global x prefetch in flight)
__device__ __forceinline__ void bar_lgkm() {
    asm volatile("s_waitcnt lgkmcnt(0)\n\ts_barrier" ::: "memory");
}

__global__ __launch_bounds__(512, 2) void gru_fused(
    const float* __restrict__ x,     // [T,B,2]
    const float* __restrict__ Wih0,  // [192,2]
    const float* __restrict__ Whh0,  // [192,64]
    const float* __restrict__ bih0,  // [192]
    const float* __restrict__ bhh0,  // [192]
    const float* __restrict__ Wih1,  // [192,64]
    const float* __restrict__ Whh1,  // [192,64]
    const float* __restrict__ bih1,  // [192]
    const float* __restrict__ bhh1,  // [192]
    const float* __restrict__ Wp,    // [128]
    const float* __restrict__ bp,    // [1]
    float* __restrict__ out)         // [B]
{
    const int tid  = threadIdx.x;
    const int wv   = tid >> 6;      // wave 0..7
    const int isL0 = (wv < 4);
    const int w4   = wv & 3;
    const int l    = tid & 63;
    const int lm   = l & 15;        // A row m / n-col within tile
    const int lq   = l >> 4;        // quad
    const int b0   = blockIdx.x * 16;
    const int j    = w4 * 16 + lm;  // hidden index this lane owns

    __shared__ short h0A[2][16 * SROW];
    __shared__ short h1A[2][16 * SROW];
    __shared__ float Pf[16][64];

    for (int idx = tid; idx < 2 * 16 * SROW; idx += 512) {
        ((short*)h0A)[idx] = 0;
        ((short*)h1A)[idx] = 0;
    }
    __syncthreads();

    const int aoff = lm * SROW + lq * 8;  // shorts; +32 for K-half 1
    const int r0   = lq * 4;              // first of this lane's 4 rows

    if (isL0) {
        // ================= layer-0 waves =================
        bf16x8 w0[3][2];   // Whh0, gate-prescaled, single bf16
#pragma unroll
        for (int g = 0; g < 3; ++g) {
            const int row = g * 64 + j;
            const float sc = (g == 2) ? SN : SRZ;
#pragma unroll
            for (int q = 0; q < 2; ++q) {
                const float* p = Whh0 + row * 64 + q * 32 + lq * 8;
                bf16x8 vh;
#pragma unroll
                for (int i = 0; i < 8; ++i) vh[i] = f2bf(p[i] * sc);
                w0[g][q] = vh;
            }
        }
        const f32x2 wr0 = splat2(SRZ * Wih0[j * 2 + 0]), wr1 = splat2(SRZ * Wih0[j * 2 + 1]);
        const f32x2 wz0 = splat2(SRZ * Wih0[(64 + j) * 2 + 0]), wz1 = splat2(SRZ * Wih0[(64 + j) * 2 + 1]);
        const f32x2 wn0 = splat2(SN * Wih0[(128 + j) * 2 + 0]), wn1 = splat2(SN * Wih0[(128 + j) * 2 + 1]);
        const float cb[3] = { SRZ * (bih0[j] + bhh0[j]),
                              SRZ * (bih0[64 + j] + bhh0[64 + j]),
                              SN  * bhh0[128 + j] };
        const f32x2 bn = splat2(SN * bih0[128 + j]);

        f32x2 h01 = {0.f, 0.f}, h23 = {0.f, 0.f};

        // x pipeline: xE/xO hold x(even t)/x(odd t); loads run 2 steps ahead.
        const float* xb_ = x + (size_t)(b0 + r0) * 2;
        f32x4 xEa = *(const f32x4*)xb_;
        f32x4 xEb = *(const f32x4*)(xb_ + 4);
        f32x4 xOa = *(const f32x4*)(xb_ + (size_t)BATCH * 2);
        f32x4 xOb = *(const f32x4*)(xb_ + (size_t)BATCH * 2 + 4);
        const float* xp = xb_ + 2 * (size_t)BATCH * 2;   // next load = x(2)

        PX pE, pO;
        // px(0) from x(0)
        {
            const f32x2 x0a = {xEa[0], xEa[2]}, x1a = {xEa[1], xEa[3]};
            const f32x2 x0b = {xEb[0], xEb[2]}, x1b = {xEb[1], xEb[3]};
            pE.gr0 = fma2(wr0, x0a, wr1 * x1a);
            pE.gz0 = fma2(wz0, x0a, wz1 * x1a);
            pE.gn0 = fma2(wn0, x0a, fma2(wn1, x1a, bn));
            pE.gr1 = fma2(wr0, x0b, wr1 * x1b);
            pE.gz1 = fma2(wz0, x0b, wz1 * x1b);
            pE.gn1 = fma2(wn0, x0b, fma2(wn1, x1b, bn));
        }

        auto l0_step = [&](int pr, bool doload, PX& u, PX& d,
                           f32x4& xla, f32x4& xlb,
                           const f32x4& xsa, const f32x4& xsb) {
            const int pw = pr ^ 1;
            const bf16x8 a00 = *(const bf16x8*)&h0A[pr][aoff];
            const bf16x8 a01 = *(const bf16x8*)&h0A[pr][aoff + 32];
            if (doload) {
                xla = *(const f32x4*)xp;
                xlb = *(const f32x4*)(xp + 4);
                xp += (size_t)BATCH * 2;
            }
            // px for NEXT step: independent of the ds_reads above — fills
            // the lgkm window before the MFMAs need the fragments.
            {
                const f32x2 x0a = {xsa[0], xsa[2]}, x1a = {xsa[1], xsa[3]};
                const f32x2 x0b = {xsb[0], xsb[2]}, x1b = {xsb[1], xsb[3]};
                d.gr0 = fma2(wr0, x0a, wr1 * x1a);
                d.gz0 = fma2(wz0, x0a, wz1 * x1a);
                d.gn0 = fma2(wn0, x0a, fma2(wn1, x1a, bn));
                d.gr1 = fma2(wr0, x0b, wr1 * x1b);
                d.gz1 = fma2(wz0, x0b, wz1 * x1b);
                d.gn1 = fma2(wn0, x0b, fma2(wn1, x1b, bn));
            }
            f32x4 hg0[3];
            __builtin_amdgcn_s_setprio(1);
#pragma unroll
            for (int g = 0; g < 3; ++g) {
                const f32x4 ci = {cb[g], cb[g], cb[g], cb[g]};
                f32x4 c;
                c = __builtin_amdgcn_mfma_f32_16x16x32_bf16(a00, w0[g][0], ci, 0, 0, 0);
                hg0[g] = __builtin_amdgcn_mfma_f32_16x16x32_bf16(a01, w0[g][1], c, 0, 0, 0);
            }
            __builtin_amdgcn_s_setprio(0);
            {   // rows r0+0, r0+1 (acc regs 0,1)
                const f32x2 hgr = {hg0[0][0], hg0[0][1]};
                const f32x2 hgz = {hg0[1][0], hg0[1][1]};
                const f32x2 hgn = {hg0[2][0], hg0[2][1]};
                const f32x2 rv = sig2(hgr + u.gr0);
                const f32x2 hv = gru_h(hgz + u.gz0, fma2(rv, hgn, u.gn0), h01);
                h01 = hv;
                const uint32_t pk = cvt_pk_bf16(hv[0], hv[1]);
                h0A[pw][(r0 + 0) * SROW + j] = (short)(pk & 0xffffu);
                h0A[pw][(r0 + 1) * SROW + j] = (short)(pk >> 16);
            }
            {   // rows r0+2, r0+3 (acc regs 2,3)
                const f32x2 hgr = {hg0[0][2], hg0[0][3]};
                const f32x2 hgz = {hg0[1][2], hg0[1][3]};
                const f32x2 hgn = {hg0[2][2], hg0[2][3]};
                const f32x2 rv = sig2(hgr + u.gr1);
                const f32x2 hv = gru_h(hgz + u.gz1, fma2(rv, hgn, u.gn1), h23);
                h23 = hv;
                const uint32_t pk = cvt_pk_bf16(hv[0], hv[1]);
                h0A[pw][(r0 + 2) * SROW + j] = (short)(pk & 0xffffu);
                h0A[pw][(r0 + 3) * SROW + j] = (short)(pk >> 16);
            }
        };

        for (int tp = 0; tp < TSTEPS / 2; ++tp) {
            const bool doload = (tp < TSTEPS / 2 - 1);
            l0_step(0, doload, pE, pO, xEa, xEb, xOa, xOb);  // t = 2tp
            bar_lgkm();
            l0_step(1, doload, pO, pE, xOa, xOb, xEa, xEb);  // t = 2tp+1
            bar_lgkm();
        }
        // t=512: L0 has no work (L1 consumes h0(511) this iter)

        const float wp0 = Wp[j];
        Pf[r0 + 0][j] = wp0 * h01[0];
        Pf[r0 + 1][j] = wp0 * h01[1];
        Pf[r0 + 2][j] = wp0 * h23[0];
        Pf[r0 + 3][j] = wp0 * h23[1];
        __syncthreads();
        __syncthreads();
    } else {
        // ================= layer-1 waves =================
        bf16x8 w1[3][2], w2[3][2];   // Wih1, Whh1, gate-prescaled, single bf16
#pragma unroll
        for (int g = 0; g < 3; ++g) {
            const int row = g * 64 + j;
            const float sc = (g == 2) ? SN : SRZ;
#pragma unroll
            for (int q = 0; q < 2; ++q) {
                const float* p1 = Wih1 + row * 64 + q * 32 + lq * 8;
                const float* p2 = Whh1 + row * 64 + q * 32 + lq * 8;
                bf16x8 v1, v2;
#pragma unroll
                for (int i = 0; i < 8; ++i) {
                    v1[i] = f2bf(p1[i] * sc);
                    v2[i] = f2bf(p2[i] * sc);
                }
                w1[g][q] = v1; w2[g][q] = v2;
            }
        }
        const float cb[3] = { SRZ * (bih1[j] + bhh1[j]),
                              SRZ * (bih1[64 + j] + bhh1[64 + j]),
                              SN  * bih1[128 + j] };
        // bhh1_n folded into hg1's C-init (multiplied by r later)
        const float ce2 = SN * bhh1[128 + j];

        f32x2 h01 = {0.f, 0.f}, h23 = {0.f, 0.f};

        auto l1_step = [&](int pr, bool doew, bool dowrite) {
            const int pw = pr ^ 1;
            // --- phase 1: h1 self-recurrence frags + hg MFMAs ---
            const bf16x8 a10 = *(const bf16x8*)&h1A[pr][aoff];
            const bf16x8 a11 = *(const bf16x8*)&h1A[pr][aoff + 32];

            f32x4 xg1[3], hg1[3];
            __builtin_amdgcn_s_setprio(1);
#pragma unroll
            for (int g = 0; g < 3; ++g) {
                const float ev = (g == 2) ? ce2 : 0.0f;
                const f32x4 ei = {ev, ev, ev, ev};
                f32x4 e;
                e = __builtin_amdgcn_mfma_f32_16x16x32_bf16(a10, w2[g][0], ei, 0, 0, 0);
                hg1[g] = __builtin_amdgcn_mfma_f32_16x16x32_bf16(a11, w2[g][1], e, 0, 0, 0);
            }
            __builtin_amdgcn_s_setprio(0);

            // --- phase 2: h0 input frags + xg MFMAs ---
            const bf16x8 a00 = *(const bf16x8*)&h0A[pr][aoff];
            const bf16x8 a01 = *(const bf16x8*)&h0A[pr][aoff + 32];

            __builtin_amdgcn_s_setprio(1);
#pragma unroll
            for (int g = 0; g < 3; ++g) {
                const f32x4 ci = {cb[g], cb[g], cb[g], cb[g]};
                f32x4 dd;
                dd = __builtin_amdgcn_mfma_f32_16x16x32_bf16(a00, w1[g][0], ci, 0, 0, 0);
                xg1[g] = __builtin_amdgcn_mfma_f32_16x16x32_bf16(a01, w1[g][1], dd, 0, 0, 0);
            }
            __builtin_amdgcn_s_setprio(0);

            if (doew) {
                {   // rows r0+0, r0+1
                    const f32x2 xgr = {xg1[0][0], xg1[0][1]}, hgr = {hg1[0][0], hg1[0][1]};
                    const f32x2 xgz = {xg1[1][0], xg1[1][1]}, hgz = {hg1[1][0], hg1[1][1]};
                    const f32x2 xgn = {xg1[2][0], xg1[2][1]}, hgn = {hg1[2][0], hg1[2][1]};
                    const f32x2 rv = sig2(xgr + hgr);
                    const f32x2 hv = gru_h(xgz + hgz, fma2(rv, hgn, xgn), h01);
                    h01 = hv;
                    if (dowrite) {
                        const uint32_t pk = cvt_pk_bf16(hv[0], hv[1]);
                        h1A[pw][(r0 + 0) * SROW + j] = (short)(pk & 0xffffu);
                        h1A[pw][(r0 + 1) * SROW + j] = (short)(pk >> 16);
                    }
                }
                {   // rows r0+2, r0+3
                    const f32x2 xgr = {xg1[0][2], xg1[0][3]}, hgr = {hg1[0][2], hg1[0][3]};
                    const f32x2 xgz = {xg1[1][2], xg1[1][3]}, hgz = {hg1[1][2], hg1[1][3]};
                    const f32x2 xgn = {xg1[2][2], xg1[2][3]}, hgn = {hg1[2][2], hg1[2][3]};
                    const f32x2 rv = sig2(xgr + hgr);
                    const f32x2 hv = gru_h(xgz + hgz, fma2(rv, hgn, xgn), h23);
                    h23 = hv;
                    if (dowrite) {
                        const uint32_t pk = cvt_pk_bf16(hv[0], hv[1]);
                        h1A[pw][(r0 + 2) * SROW + j] = (short)(pk & 0xffffu);
                        h1A[pw][(r0 + 3) * SROW + j] = (short)(pk >> 16);
                    }
                }
            }
        };

        for (int tp = 0; tp < TSTEPS / 2; ++tp) {
            l1_step(0, tp > 0, true);   // t = 2tp
            bar_lgkm();
            l1_step(1, true, true);     // t = 2tp+1
            bar_lgkm();
        }
        l1_step(0, true, false);        // t = 512: last L1 update, no store

        __syncthreads();                // Pf written by L0 waves
        const float wp1 = Wp[64 + j];
        Pf[r0 + 0][j] += wp1 * h01[0];
        Pf[r0 + 1][j] += wp1 * h01[1];
        Pf[r0 + 2][j] += wp1 * h23[0];
        Pf[r0 + 3][j] += wp1 * h23[1];
        __syncthreads();
    }

    // ---- final reduce: out[b] = sum_j Pf[row][j] + bp ----
    if (tid < 16) {
        float s = bp[0];
#pragma unroll 8
        for (int k = 0; k < 64; ++k) s += Pf[tid][k];
        out[b0 + tid] = s;
    }
}

extern "C" void kernel_launch(void* const* d_in, const int* in_sizes, int n_in,
                              void* d_out, int out_size, void* d_ws, size_t ws_size,
                              hipStream_t stream) {
    (void)in_sizes; (void)n_in; (void)out_size; (void)d_ws; (void)ws_size;
    gru_fused<<<dim3(BATCH / 16), dim3(512), 0, stream>>>(
        (const float*)d_in[0], (const float*)d_in[1], (const float*)d_in[2],
        (const float*)d_in[3], (const float*)d_in[4], (const float*)d_in[5],
        (const float*)d_in[6], (const float*)d_in[7], (const float*)d_in[8],
        (const float*)d_in[9], (const float*)d_in[10], (float*)d_out);
}

// Round 9
// 330.752 us; speedup vs baseline: 1.4582x; 1.0277x over previous
//
#include <hip/hip_runtime.h>
#include <stdint.h>

#define TSTEPS 512
#define BATCH  4096
#define SROW 76                      /* LDS row stride in shorts (R18 bank fix) */
// R24 = exact R19 revert — the measured optimum of this design space
// (294 us steady / 327.6 headline). Locking it in as final.
//
// WHY this is the floor (measured, not assumed):
//  wall = 1376 cyc/CU-step: ~738 VALU-pipe occupancy (≈320 trans @1/4 rate
//  + ≈420 regular) + ~640 dual-wave stall (post-barrier ds_read latency,
//  MFMA chain latency, serial EW chain tails). Escapes all measured:
//  - R18: LDS bank conflicts eliminated (1.27e7 -> 8e4), stride 76.
//  - R18: trans at algebraic floor 5/elem (rational z/n fusion, 1 rcp).
//  - R19: x-side gates precomputed in MFMA shadow; buffer parity static.
//  - R20/R21/R22: fewer rows/wave + more waves/SIMD (permlane-compacted EW,
//    role-diverse SIMDs): +26-58% — per-wave fixed overhead duplicates
//    faster than TLP fills stall (rows/CU pinned at 16 by grid=256 CUs).
//  - R23: instruction reorders (px hoist, L1 read split): +5% — compiler
//    already schedules these optimally.
//  - 32 rows/CU rejected by model: halves grid -> doubles per-CU trans.
//  Issue-bound floor ~150 us needs zero sync/latency exposure across 513
//  serial barrier steps — no sub-block barrier exists on gfx950.
//
// Structure: grid 256 x 512thr, 16 batch rows/block (full 16x16x32 A-tile),
// 1 block/CU, 2 waves/SIMD (one L0 + one L1 -> role diversity per SIMD).
// Waves 0-3: layer-0 (hg MFMAs + EW + x prefetch/px pipeline).
// Waves 4-7: layer-1 (xg+hg MFMAs + EW), one step behind L0.
// h exchanged via double-buffered bf16 LDS, stride-76 rows (conflict-free
// b128 frag reads AND b16 h writes). EW: packed f32x2, exp2-prescaled
// weights (SRZ/SN), sigmoid = rcp(1+exp2(y)), fused z/n/h' rational form,
// v_cvt_pk_bf16_f32 stores, lgkm-only barrier (x prefetch stays in flight).

typedef __attribute__((ext_vector_type(8))) short bf16x8;
typedef __attribute__((ext_vector_type(4))) float f32x4;
typedef __attribute__((ext_vector_type(2))) float f32x2;

#define SRZ (-1.4426950408889634f)   /* -log2(e): r,z gates */
#define SN  ( 2.8853900817779268f)   /* 2*log2(e): n gate   */

struct PX { f32x2 gr0, gz0, gn0, gr1, gz1, gn1; };

__device__ __forceinline__ short f2bf(float f) {
    uint32_t u = __float_as_uint(f);
    uint32_t r = (u + 0x7fffu + ((u >> 16) & 1u)) >> 16;
    return (short)r;
}
// packed f32x2 -> 2x bf16 (RNE), lo = a, hi = b
__device__ __forceinline__ uint32_t cvt_pk_bf16(float a, float b) {
    uint32_t r;
    asm("v_cvt_pk_bf16_f32 %0, %1, %2" : "=v"(r) : "v"(a), "v"(b));
    return r;
}
__device__ __forceinline__ float fast_rcp(float x) { return __builtin_amdgcn_rcpf(x); }
#if __has_builtin(__builtin_amdgcn_exp2f)
__device__ __forceinline__ float exp2_fast(float x) { return __builtin_amdgcn_exp2f(x); }
#else
__device__ __forceinline__ float exp2_fast(float x) { return __expf(x * 0.6931471805599453f); }
#endif

__device__ __forceinline__ f32x2 fma2(f32x2 a, f32x2 b, f32x2 c) {
    return __builtin_elementwise_fma(a, b, c);
}
__device__ __forceinline__ f32x2 splat2(float s) { return (f32x2){s, s}; }
__device__ __forceinline__ f32x2 exp22(f32x2 y) {
    return (f32x2){exp2_fast(y[0]), exp2_fast(y[1])};
}
__device__ __forceinline__ f32x2 rcp2(f32x2 y) {
    return (f32x2){fast_rcp(y[0]), fast_rcp(y[1])};
}
// sigmoid of pre-scaled arg: rcp(1 + exp2(y))
__device__ __forceinline__ f32x2 sig2(f32x2 y) {
    return rcp2(exp22(y) + splat2(1.0f));
}
// fused z/n/h' update: yz pre-scaled by SRZ, yn pre-scaled by SN.
// z = 1/(1+A), n = (B-1)/(B+1); h' = (1-z)n + z*h
//    = [A(B-1) + h(B+1)] / [(B+1)(A+1)]
__device__ __forceinline__ f32x2 gru_h(f32x2 yz, f32x2 yn, f32x2 h) {
    const f32x2 A = exp22(yz);
    const f32x2 B = exp22(yn);
    const f32x2 P = A * B;
    const f32x2 u = (P - A) + fma2(h, B, h);            // A*B - A + h*B + h
    const f32x2 d = (P + A) + (B + splat2(1.0f));       // A*B + A + B + 1
    return u * rcp2(d);
}
// in-loop barrier: drain LDS only (keep global x prefetch in flight)
__device__ __forceinline__ void bar_lgkm() {
    asm volatile("s_waitcnt lgkmcnt(0)\n\ts_barrier" ::: "memory");
}

__global__ __launch_bounds__(512, 2) void gru_fused(
    const float* __restrict__ x,     // [T,B,2]
    const float* __restrict__ Wih0,  // [192,2]
    const float* __restrict__ Whh0,  // [192,64]
    const float* __restrict__ bih0,  // [192]
    const float* __restrict__ bhh0,  // [192]
    const float* __restrict__ Wih1,  // [192,64]
    const float* __restrict__ Whh1,  // [192,64]
    const float* __restrict__ bih1,  // [192]
    const float* __restrict__ bhh1,  // [192]
    const float* __restrict__ Wp,    // [128]
    const float* __restrict__ bp,    // [1]
    float* __restrict__ out)         // [B]
{
    const int tid  = threadIdx.x;
    const int wv   = tid >> 6;      // wave 0..7
    const int isL0 = (wv < 4);
    const int w4   = wv & 3;
    const int l    = tid & 63;
    const int lm   = l & 15;        // A row m / n-col within tile
    const int lq   = l >> 4;        // quad
    const int b0   = blockIdx.x * 16;
    const int j    = w4 * 16 + lm;  // hidden index this lane owns

    __shared__ short h0A[2][16 * SROW];
    __shared__ short h1A[2][16 * SROW];
    __shared__ float Pf[16][64];

    for (int idx = tid; idx < 2 * 16 * SROW; idx += 512) {
        ((short*)h0A)[idx] = 0;
        ((short*)h1A)[idx] = 0;
    }
    __syncthreads();

    const int aoff = lm * SROW + lq * 8;  // shorts; +32 for K-half 1
    const int r0   = lq * 4;              // first of this lane's 4 rows

    if (isL0) {
        // ================= layer-0 waves =================
        bf16x8 w0[3][2];   // Whh0, gate-prescaled, single bf16
#pragma unroll
        for (int g = 0; g < 3; ++g) {
            const int row = g * 64 + j;
            const float sc = (g == 2) ? SN : SRZ;
#pragma unroll
            for (int q = 0; q < 2; ++q) {
                const float* p = Whh0 + row * 64 + q * 32 + lq * 8;
                bf16x8 vh;
#pragma unroll
                for (int i = 0; i < 8; ++i) vh[i] = f2bf(p[i] * sc);
                w0[g][q] = vh;
            }
        }
        const f32x2 wr0 = splat2(SRZ * Wih0[j * 2 + 0]), wr1 = splat2(SRZ * Wih0[j * 2 + 1]);
        const f32x2 wz0 = splat2(SRZ * Wih0[(64 + j) * 2 + 0]), wz1 = splat2(SRZ * Wih0[(64 + j) * 2 + 1]);
        const f32x2 wn0 = splat2(SN * Wih0[(128 + j) * 2 + 0]), wn1 = splat2(SN * Wih0[(128 + j) * 2 + 1]);
        const float cb[3] = { SRZ * (bih0[j] + bhh0[j]),
                              SRZ * (bih0[64 + j] + bhh0[64 + j]),
                              SN  * bhh0[128 + j] };
        const f32x2 bn = splat2(SN * bih0[128 + j]);

        f32x2 h01 = {0.f, 0.f}, h23 = {0.f, 0.f};

        // x pipeline: xE/xO hold x(even t)/x(odd t); loads run 2 steps ahead.
        const float* xb_ = x + (size_t)(b0 + r0) * 2;
        f32x4 xEa = *(const f32x4*)xb_;
        f32x4 xEb = *(const f32x4*)(xb_ + 4);
        f32x4 xOa = *(const f32x4*)(xb_ + (size_t)BATCH * 2);
        f32x4 xOb = *(const f32x4*)(xb_ + (size_t)BATCH * 2 + 4);
        const float* xp = xb_ + 2 * (size_t)BATCH * 2;   // next load = x(2)

        PX pE, pO;
        // px(0) from x(0)
        {
            const f32x2 x0a = {xEa[0], xEa[2]}, x1a = {xEa[1], xEa[3]};
            const f32x2 x0b = {xEb[0], xEb[2]}, x1b = {xEb[1], xEb[3]};
            pE.gr0 = fma2(wr0, x0a, wr1 * x1a);
            pE.gz0 = fma2(wz0, x0a, wz1 * x1a);
            pE.gn0 = fma2(wn0, x0a, fma2(wn1, x1a, bn));
            pE.gr1 = fma2(wr0, x0b, wr1 * x1b);
            pE.gz1 = fma2(wz0, x0b, wz1 * x1b);
            pE.gn1 = fma2(wn0, x0b, fma2(wn1, x1b, bn));
        }

        auto l0_step = [&](int pr, bool doload, PX& u, PX& d,
                           f32x4& xla, f32x4& xlb,
                           const f32x4& xsa, const f32x4& xsb) {
            const int pw = pr ^ 1;
            const bf16x8 a00 = *(const bf16x8*)&h0A[pr][aoff];
            const bf16x8 a01 = *(const bf16x8*)&h0A[pr][aoff + 32];
            if (doload) {
                xla = *(const f32x4*)xp;
                xlb = *(const f32x4*)(xp + 4);
                xp += (size_t)BATCH * 2;
            }
            f32x4 hg0[3];
            __builtin_amdgcn_s_setprio(1);
#pragma unroll
            for (int g = 0; g < 3; ++g) {
                const f32x4 ci = {cb[g], cb[g], cb[g], cb[g]};
                f32x4 c;
                c = __builtin_amdgcn_mfma_f32_16x16x32_bf16(a00, w0[g][0], ci, 0, 0, 0);
                hg0[g] = __builtin_amdgcn_mfma_f32_16x16x32_bf16(a01, w0[g][1], c, 0, 0, 0);
            }
            __builtin_amdgcn_s_setprio(0);
            // px for NEXT step (independent of MFMAs -> fills their shadow)
            {
                const f32x2 x0a = {xsa[0], xsa[2]}, x1a = {xsa[1], xsa[3]};
                const f32x2 x0b = {xsb[0], xsb[2]}, x1b = {xsb[1], xsb[3]};
                d.gr0 = fma2(wr0, x0a, wr1 * x1a);
                d.gz0 = fma2(wz0, x0a, wz1 * x1a);
                d.gn0 = fma2(wn0, x0a, fma2(wn1, x1a, bn));
                d.gr1 = fma2(wr0, x0b, wr1 * x1b);
                d.gz1 = fma2(wz0, x0b, wz1 * x1b);
                d.gn1 = fma2(wn0, x0b, fma2(wn1, x1b, bn));
            }
            {   // rows r0+0, r0+1 (acc regs 0,1)
                const f32x2 hgr = {hg0[0][0], hg0[0][1]};
                const f32x2 hgz = {hg0[1][0], hg0[1][1]};
                const f32x2 hgn = {hg0[2][0], hg0[2][1]};
                const f32x2 rv = sig2(hgr + u.gr0);
                const f32x2 hv = gru_h(hgz + u.gz0, fma2(rv, hgn, u.gn0), h01);
                h01 = hv;
                const uint32_t pk = cvt_pk_bf16(hv[0], hv[1]);
                h0A[pw][(r0 + 0) * SROW + j] = (short)(pk & 0xffffu);
                h0A[pw][(r0 + 1) * SROW + j] = (short)(pk >> 16);
            }
            {   // rows r0+2, r0+3 (acc regs 2,3)
                const f32x2 hgr = {hg0[0][2], hg0[0][3]};
                const f32x2 hgz = {hg0[1][2], hg0[1][3]};
                const f32x2 hgn = {hg0[2][2], hg0[2][3]};
                const f32x2 rv = sig2(hgr + u.gr1);
                const f32x2 hv = gru_h(hgz + u.gz1, fma2(rv, hgn, u.gn1), h23);
                h23 = hv;
                const uint32_t pk = cvt_pk_bf16(hv[0], hv[1]);
                h0A[pw][(r0 + 2) * SROW + j] = (short)(pk & 0xffffu);
                h0A[pw][(r0 + 3) * SROW + j] = (short)(pk >> 16);
            }
        };

        for (int tp = 0; tp < TSTEPS / 2; ++tp) {
            const bool doload = (tp < TSTEPS / 2 - 1);
            l0_step(0, doload, pE, pO, xEa, xEb, xOa, xOb);  // t = 2tp
            bar_lgkm();
            l0_step(1, doload, pO, pE, xOa, xOb, xEa, xEb);  // t = 2tp+1
            bar_lgkm();
        }
        // t=512: L0 has no work (L1 consumes h0(511) this iter)

        const float wp0 = Wp[j];
        Pf[r0 + 0][j] = wp0 * h01[0];
        Pf[r0 + 1][j] = wp0 * h01[1];
        Pf[r0 + 2][j] = wp0 * h23[0];
        Pf[r0 + 3][j] = wp0 * h23[1];
        __syncthreads();
        __syncthreads();
    } else {
        // ================= layer-1 waves =================
        bf16x8 w1[3][2], w2[3][2];   // Wih1, Whh1, gate-prescaled, single bf16
#pragma unroll
        for (int g = 0; g < 3; ++g) {
            const int row = g * 64 + j;
            const float sc = (g == 2) ? SN : SRZ;
#pragma unroll
            for (int q = 0; q < 2; ++q) {
                const float* p1 = Wih1 + row * 64 + q * 32 + lq * 8;
                const float* p2 = Whh1 + row * 64 + q * 32 + lq * 8;
                bf16x8 v1, v2;
#pragma unroll
                for (int i = 0; i < 8; ++i) {
                    v1[i] = f2bf(p1[i] * sc);
                    v2[i] = f2bf(p2[i] * sc);
                }
                w1[g][q] = v1; w2[g][q] = v2;
            }
        }
        const float cb[3] = { SRZ * (bih1[j] + bhh1[j]),
                              SRZ * (bih1[64 + j] + bhh1[64 + j]),
                              SN  * bih1[128 + j] };
        // bhh1_n folded into hg1's C-init (multiplied by r later:
        // n = tanh(r*(Whh1n.h + bhh1n) + Wih1n.h0 + bih1n))
        const float ce2 = SN * bhh1[128 + j];

        f32x2 h01 = {0.f, 0.f}, h23 = {0.f, 0.f};

        auto l1_step = [&](int pr, bool doew, bool dowrite) {
            const int pw = pr ^ 1;
            // all 4 A-frag reads upfront (conflict-free since R18)
            const bf16x8 a10 = *(const bf16x8*)&h1A[pr][aoff];
            const bf16x8 a11 = *(const bf16x8*)&h1A[pr][aoff + 32];
            const bf16x8 a00 = *(const bf16x8*)&h0A[pr][aoff];
            const bf16x8 a01 = *(const bf16x8*)&h0A[pr][aoff + 32];

            f32x4 xg1[3], hg1[3];
            __builtin_amdgcn_s_setprio(1);
#pragma unroll
            for (int g = 0; g < 3; ++g) {
                const float ev = (g == 2) ? ce2 : 0.0f;
                const f32x4 ei = {ev, ev, ev, ev};
                f32x4 e;
                e = __builtin_amdgcn_mfma_f32_16x16x32_bf16(a10, w2[g][0], ei, 0, 0, 0);
                hg1[g] = __builtin_amdgcn_mfma_f32_16x16x32_bf16(a11, w2[g][1], e, 0, 0, 0);
            }
#pragma unroll
            for (int g = 0; g < 3; ++g) {
                const f32x4 ci = {cb[g], cb[g], cb[g], cb[g]};
                f32x4 d;
                d = __builtin_amdgcn_mfma_f32_16x16x32_bf16(a00, w1[g][0], ci, 0, 0, 0);
                xg1[g] = __builtin_amdgcn_mfma_f32_16x16x32_bf16(a01, w1[g][1], d, 0, 0, 0);
            }
            __builtin_amdgcn_s_setprio(0);

            if (doew) {
                {   // rows r0+0, r0+1
                    const f32x2 xgr = {xg1[0][0], xg1[0][1]}, hgr = {hg1[0][0], hg1[0][1]};
                    const f32x2 xgz = {xg1[1][0], xg1[1][1]}, hgz = {hg1[1][0], hg1[1][1]};
                    const f32x2 xgn = {xg1[2][0], xg1[2][1]}, hgn = {hg1[2][0], hg1[2][1]};
                    const f32x2 rv = sig2(xgr + hgr);
                    const f32x2 hv = gru_h(xgz + hgz, fma2(rv, hgn, xgn), h01);
                    h01 = hv;
                    if (dowrite) {
                        const uint32_t pk = cvt_pk_bf16(hv[0], hv[1]);
                        h1A[pw][(r0 + 0) * SROW + j] = (short)(pk & 0xffffu);
                        h1A[pw][(r0 + 1) * SROW + j] = (short)(pk >> 16);
                    }
                }
                {   // rows r0+2, r0+3
                    const f32x2 xgr = {xg1[0][2], xg1[0][3]}, hgr = {hg1[0][2], hg1[0][3]};
                    const f32x2 xgz = {xg1[1][2], xg1[1][3]}, hgz = {hg1[1][2], hg1[1][3]};
                    const f32x2 xgn = {xg1[2][2], xg1[2][3]}, hgn = {hg1[2][2], hg1[2][3]};
                    const f32x2 rv = sig2(xgr + hgr);
                    const f32x2 hv = gru_h(xgz + hgz, fma2(rv, hgn, xgn), h23);
                    h23 = hv;
                    if (dowrite) {
                        const uint32_t pk = cvt_pk_bf16(hv[0], hv[1]);
                        h1A[pw][(r0 + 2) * SROW + j] = (short)(pk & 0xffffu);
                        h1A[pw][(r0 + 3) * SROW + j] = (short)(pk >> 16);
                    }
                }
            }
        };

        for (int tp = 0; tp < TSTEPS / 2; ++tp) {
            l1_step(0, tp > 0, true);   // t = 2tp
            bar_lgkm();
            l1_step(1, true, true);     // t = 2tp+1
            bar_lgkm();
        }
        l1_step(0, true, false);        // t = 512: last L1 update, no store

        __syncthreads();                // Pf written by L0 waves
        const float wp1 = Wp[64 + j];
        Pf[r0 + 0][j] += wp1 * h01[0];
        Pf[r0 + 1][j] += wp1 * h01[1];
        Pf[r0 + 2][j] += wp1 * h23[0];
        Pf[r0 + 3][j] += wp1 * h23[1];
        __syncthreads();
    }

    // ---- final reduce: out[b] = sum_j Pf[row][j] + bp ----
    if (tid < 16) {
        float s = bp[0];
#pragma unroll 8
        for (int k = 0; k < 64; ++k) s += Pf[tid][k];
        out[b0 + tid] = s;
    }
}

extern "C" void kernel_launch(void* const* d_in, const int* in_sizes, int n_in,
                              void* d_out, int out_size, void* d_ws, size_t ws_size,
                              hipStream_t stream) {
    (void)in_sizes; (void)n_in; (void)out_size; (void)d_ws; (void)ws_size;
    gru_fused<<<dim3(BATCH / 16), dim3(512), 0, stream>>>(
        (const float*)d_in[0], (const float*)d_in[1], (const float*)d_in[2],
        (const float*)d_in[3], (const float*)d_in[4], (const float*)d_in[5],
        (const float*)d_in[6], (const float*)d_in[7], (const float*)d_in[8],
        (const float*)d_in[9], (const float*)d_in[10], (float*)d_out);
}